// Round 2
// baseline (437.941 us; speedup 1.0000x reference)
//
#include <hip/hip_runtime.h>
#include <math.h>

#define BB 2
#define NN 384
#define ND 8
#define CD 16
#define HH 128
#define LL 4
#define TT 100
#define NPB 3   // nodes per block in fused layer kernel (256 blocks * 3 = 768)

__device__ __forceinline__ float silu_f(float x) {
    float s = 1.0f / (1.0f + __expf(-x));
    return x * s;
}

// ---------------- per-batch prep: alpha_bar, mask sum, time+cond MLPs, zero accums ----------------
__global__ void k_prep(const float* __restrict__ mask, const float* __restrict__ condition,
                       const int* __restrict__ timesteps,
                       const float* __restrict__ time_w1, const float* __restrict__ time_b1,
                       const float* __restrict__ time_w2, const float* __restrict__ time_b2,
                       const float* __restrict__ cond_w1, const float* __restrict__ cond_b1,
                       const float* __restrict__ cond_w2, const float* __restrict__ cond_b2,
                       float* __restrict__ tc, float* __restrict__ scal, float* __restrict__ accums) {
    int b = blockIdx.x;
    int t = threadIdx.x; // 0..127
    __shared__ float sh[HH];
    __shared__ float sh2[HH];
    __shared__ float shc[CD];
    __shared__ float red[HH];

    if (b == 0 && t < 2) accums[t] = 0.0f;

    int ts = timesteps[b];
    float ab = 1.0f;
    for (int k = 0; k <= ts; ++k) {
        float beta = 1e-4f + (0.02f - 1e-4f) * ((float)k / (float)(TT - 1));
        ab *= (1.0f - beta);
    }
    if (t == 0) {
        scal[b * 4 + 0] = sqrtf(ab);
        scal[b * 4 + 1] = sqrtf(1.0f - ab);
    }
    float m = 0.0f;
    for (int j = t; j < NN; j += HH) m += mask[b * NN + j];
    red[t] = m;
    __syncthreads();
    for (int s = 64; s > 0; s >>= 1) {
        if (t < s) red[t] += red[t + s];
        __syncthreads();
    }
    if (t == 0) scal[b * 4 + 2] = red[0];

    const int half = HH / 2;
    float factor = logf(10000.0f) / (float)(half - 1);
    float tf = (float)ts;
    float temb;
    if (t < half) temb = sinf(tf * __expf(-factor * (float)t));
    else          temb = cosf(tf * __expf(-factor * (float)(t - half)));
    sh[t] = temb;
    if (t < CD) shc[t] = condition[b * CD + t];
    __syncthreads();

    float acc = time_b1[t];
    for (int k = 0; k < HH; ++k) acc += sh[k] * time_w1[k * HH + t];
    sh2[t] = silu_f(acc);
    __syncthreads();
    float acc2 = time_b2[t];
    for (int k = 0; k < HH; ++k) acc2 += sh2[k] * time_w2[k * HH + t];
    float acc3 = cond_b1[t];
    for (int k = 0; k < CD; ++k) acc3 += shc[k] * cond_w1[k * HH + t];
    __syncthreads();
    sh[t] = silu_f(acc3);
    __syncthreads();
    float acc4 = cond_b2[t];
    for (int k = 0; k < HH; ++k) acc4 += sh[k] * cond_w2[k * HH + t];

    tc[b * HH + t] = acc2 + acc4;
}

// ---------------- per-node: noising + nodep MLP + add time/cond + layer-0 ai/aj ----------------
__global__ void k_node_init(const float* __restrict__ node_features, const float* __restrict__ positions,
                            const float* __restrict__ feature_noise, const float* __restrict__ position_noise,
                            const float* __restrict__ nodep_w1, const float* __restrict__ nodep_b1,
                            const float* __restrict__ nodep_w2, const float* __restrict__ nodep_b2,
                            const float* __restrict__ tc, const float* __restrict__ scal,
                            const float* __restrict__ ew1_0, const float* __restrict__ eb1_0,
                            float* __restrict__ state, float* __restrict__ npos,
                            float* __restrict__ ai0, float* __restrict__ aj0) {
    int idx = blockIdx.x;
    int b = idx / NN;
    int t = threadIdx.x;
    float sab = scal[b * 4 + 0], s1ab = scal[b * 4 + 1];
    __shared__ float x[ND + 2];
    __shared__ float h1[HH];
    __shared__ float sstate[HH];
    if (t < ND) {
        x[t] = sab * node_features[idx * ND + t] + s1ab * feature_noise[idx * ND + t];
    } else if (t < ND + 2) {
        int d = t - ND;
        float p = sab * positions[idx * 2 + d] + s1ab * position_noise[idx * 2 + d];
        x[t] = p;
        npos[idx * 2 + d] = p;
    }
    __syncthreads();
    float acc = nodep_b1[t];
    for (int k = 0; k < ND + 2; ++k) acc += x[k] * nodep_w1[k * HH + t];
    h1[t] = silu_f(acc);
    __syncthreads();
    float acc2 = nodep_b2[t];
    for (int k = 0; k < HH; ++k) acc2 += h1[k] * nodep_w2[k * HH + t];
    float st = acc2 + tc[b * HH + t];
    state[idx * HH + t] = st;
    sstate[t] = st;
    __syncthreads();
    // layer-0 edge projections
    float a1 = eb1_0[t];
    float a2 = 0.0f;
    for (int k = 0; k < HH; ++k) {
        float sk = sstate[k];
        a1 += sk * ew1_0[k * HH + t];
        a2 += sk * ew1_0[(HH + k) * HH + t];
    }
    ai0[idx * HH + t] = a1;
    aj0[idx * HH + t] = a2;
}

// ---------------- pairwise distances ----------------
__global__ void k_dist(const float* __restrict__ npos, float* __restrict__ dist) {
    int idx = blockIdx.x * blockDim.x + threadIdx.x;
    if (idx >= BB * NN * NN) return;
    int b = idx / (NN * NN);
    int r = idx % (NN * NN);
    int i = r / NN, j = r % NN;
    float dx = npos[(b * NN + i) * 2 + 0] - npos[(b * NN + j) * 2 + 0];
    float dy = npos[(b * NN + i) * 2 + 1] - npos[(b * NN + j) * 2 + 1];
    dist[idx] = sqrtf(dx * dx + dy * dy + 1e-12f);
}

// ---------------- fused layer: edge sum + agg + node MLP + state update + next ai/aj ----------------
template<bool LAST>
__global__ __launch_bounds__(512, 1) void k_layer(
    const float* __restrict__ ai_in, const float* __restrict__ aj_in,
    float* __restrict__ ai_out, float* __restrict__ aj_out,
    const float* __restrict__ dist, const float* __restrict__ mask,
    const float* __restrict__ scal,
    const float* __restrict__ wd,
    const float* __restrict__ ew2, const float* __restrict__ eb2,
    const float* __restrict__ nw1, const float* __restrict__ nb1,
    const float* __restrict__ nw2, const float* __restrict__ nb2,
    const float* __restrict__ ew1n, const float* __restrict__ eb1n,
    float* __restrict__ state)
{
    const int tid = threadIdx.x;
    const int t = tid & 127;
    const int g = tid >> 7;          // 0..3
    const int b0 = blockIdx.x * NPB; // global node base (768 = 256*3; batch-aligned since 384%3==0)
    const int b = b0 / NN;

    __shared__ float wbuf[2 * HH * HH];   // 128 KB staging
    __shared__ float sst[NPB][HH];
    __shared__ float sS[NPB][HH];
    __shared__ float sagg[NPB][HH];
    __shared__ float red3[NPB][4][HH];

    if (g < NPB) sst[g][t] = state[(b0 + g) * HH + t];

    // ---- P1: edge sums S_n[t] = sum_j m_j silu(ai_n + aj_j + d_nj*wd + (eb1 folded in ai)) ----
    const float wdt = wd[t];
    const float* ajb = aj_in + (size_t)b * NN * HH;
    const float* mb = mask + b * NN;
    const float av0 = ai_in[(b0 + 0) * HH + t];
    const float av1 = ai_in[(b0 + 1) * HH + t];
    const float av2 = ai_in[(b0 + 2) * HH + t];
    const float* d0 = dist + (size_t)(b0 + 0) * NN;
    const float* d1 = dist + (size_t)(b0 + 1) * NN;
    const float* d2 = dist + (size_t)(b0 + 2) * NN;
    float ac0 = 0.0f, ac1 = 0.0f, ac2 = 0.0f;
    for (int j = g; j < NN; j += 4) {
        float mj = mb[j];
        float a = ajb[(size_t)j * HH + t];
        ac0 += mj * silu_f(av0 + a + d0[j] * wdt);
        ac1 += mj * silu_f(av1 + a + d1[j] * wdt);
        ac2 += mj * silu_f(av2 + a + d2[j] * wdt);
    }
    red3[0][g][t] = ac0; red3[1][g][t] = ac1; red3[2][g][t] = ac2;
    __syncthreads();
    if (g < NPB) sS[g][t] = red3[g][0][t] + red3[g][1][t] + red3[g][2][t] + red3[g][3][t];
    // stage ew2 (wbuf first use)
    for (int i2 = tid; i2 < HH * HH / 4; i2 += 512) ((float4*)wbuf)[i2] = ((const float4*)ew2)[i2];
    __syncthreads();

    // ---- P2: agg = mi*(S@ew2 + msum*eb2)/denom ----
    {
        float p0 = 0.0f, p1 = 0.0f, p2 = 0.0f;
        const int k0 = g * 32;
        for (int k = k0; k < k0 + 32; ++k) {
            float w = wbuf[k * HH + t];
            p0 += sS[0][k] * w; p1 += sS[1][k] * w; p2 += sS[2][k] * w;
        }
        red3[0][g][t] = p0; red3[1][g][t] = p1; red3[2][g][t] = p2;
    }
    __syncthreads();
    const float msum = scal[b * 4 + 2];
    if (g < NPB) {
        float mi = mask[b0 + g];
        float denom = fmaxf(mi * msum, 1.0f);
        float a = red3[g][0][t] + red3[g][1][t] + red3[g][2][t] + red3[g][3][t] + msum * eb2[t];
        sagg[g][t] = mi * a / denom;
    }
    // stage nw1 (256x128) — previous wbuf reads finished before last sync
    for (int i2 = tid; i2 < 2 * HH * HH / 4; i2 += 512) ((float4*)wbuf)[i2] = ((const float4*)nw1)[i2];
    __syncthreads();

    // ---- P3: h = silu([st, agg] @ nw1 + nb1) ----
    {
        float p0 = 0.0f, p1 = 0.0f, p2 = 0.0f;
        const int r0 = g * 64;
        for (int r = r0; r < r0 + 64; ++r) {
            float w = wbuf[r * HH + t];
            float i0, i1, i2v;
            if (r < HH) { i0 = sst[0][r]; i1 = sst[1][r]; i2v = sst[2][r]; }
            else        { i0 = sagg[0][r - HH]; i1 = sagg[1][r - HH]; i2v = sagg[2][r - HH]; }
            p0 += i0 * w; p1 += i1 * w; p2 += i2v * w;
        }
        red3[0][g][t] = p0; red3[1][g][t] = p1; red3[2][g][t] = p2;
    }
    __syncthreads();
    if (g < NPB) sS[g][t] = silu_f(red3[g][0][t] + red3[g][1][t] + red3[g][2][t] + red3[g][3][t] + nb1[t]);
    // stage nw2
    for (int i2 = tid; i2 < HH * HH / 4; i2 += 512) ((float4*)wbuf)[i2] = ((const float4*)nw2)[i2];
    __syncthreads();

    // ---- P4: upd = h@nw2 + nb2 ; newstate = st + upd*mi ----
    {
        float p0 = 0.0f, p1 = 0.0f, p2 = 0.0f;
        const int k0 = g * 32;
        for (int k = k0; k < k0 + 32; ++k) {
            float w = wbuf[k * HH + t];
            p0 += sS[0][k] * w; p1 += sS[1][k] * w; p2 += sS[2][k] * w;
        }
        red3[0][g][t] = p0; red3[1][g][t] = p1; red3[2][g][t] = p2;
    }
    __syncthreads();
    if (g < NPB) {
        float mi = mask[b0 + g];
        float upd = red3[g][0][t] + red3[g][1][t] + red3[g][2][t] + red3[g][3][t] + nb2[t];
        float ns = sst[g][t] + upd * mi;
        state[(b0 + g) * HH + t] = ns;
        sst[g][t] = ns;
    }

    if (!LAST) {
        // stage next layer ew1 rows 0..255
        for (int i2 = tid; i2 < 2 * HH * HH / 4; i2 += 512) ((float4*)wbuf)[i2] = ((const float4*)ew1n)[i2];
        __syncthreads();
        // ai' = newst @ ew1n[:H] + eb1n
        {
            float p0 = 0.0f, p1 = 0.0f, p2 = 0.0f;
            const int k0 = g * 32;
            for (int k = k0; k < k0 + 32; ++k) {
                float w = wbuf[k * HH + t];
                p0 += sst[0][k] * w; p1 += sst[1][k] * w; p2 += sst[2][k] * w;
            }
            red3[0][g][t] = p0; red3[1][g][t] = p1; red3[2][g][t] = p2;
        }
        __syncthreads();
        if (g < NPB) ai_out[(b0 + g) * HH + t] =
            red3[g][0][t] + red3[g][1][t] + red3[g][2][t] + red3[g][3][t] + eb1n[t];
        __syncthreads();
        // aj' = newst @ ew1n[H:2H]
        {
            float p0 = 0.0f, p1 = 0.0f, p2 = 0.0f;
            const int k0 = g * 32;
            for (int k = k0; k < k0 + 32; ++k) {
                float w = wbuf[(HH + k) * HH + t];
                p0 += sst[0][k] * w; p1 += sst[1][k] * w; p2 += sst[2][k] * w;
            }
            red3[0][g][t] = p0; red3[1][g][t] = p1; red3[2][g][t] = p2;
        }
        __syncthreads();
        if (g < NPB) aj_out[(b0 + g) * HH + t] =
            red3[g][0][t] + red3[g][1][t] + red3[g][2][t] + red3[g][3][t];
    }
}

// ---------------- heads: pred_fn / pred_pn losses ----------------
__global__ void k_heads(const float* __restrict__ state, const float* __restrict__ mask,
                        const float* __restrict__ feature_noise, const float* __restrict__ position_noise,
                        const float* __restrict__ fw1, const float* __restrict__ fb1,
                        const float* __restrict__ fw2, const float* __restrict__ fb2,
                        const float* __restrict__ pw1, const float* __restrict__ pb1,
                        const float* __restrict__ pw2, const float* __restrict__ pb2,
                        float* __restrict__ accums) {
    int idx = blockIdx.x;
    int b = idx / NN, i = idx % NN;
    int t = threadIdx.x;
    __shared__ float ss[HH], h1[HH], h2[HH];
    __shared__ float lred[2];
    ss[t] = state[idx * HH + t];
    __syncthreads();
    float a = fb1[t];
    for (int k = 0; k < HH; ++k) a += ss[k] * fw1[k * HH + t];
    h1[t] = silu_f(a);
    float a2 = pb1[t];
    for (int k = 0; k < HH; ++k) a2 += ss[k] * pw1[k * HH + t];
    h2[t] = silu_f(a2);
    if (t == 0) { lred[0] = 0.0f; lred[1] = 0.0f; }
    __syncthreads();
    float mi = mask[b * NN + i];
    if (t < ND) {
        float o = fb2[t];
        for (int k = 0; k < HH; ++k) o += h1[k] * fw2[k * ND + t];
        float d = o - feature_noise[idx * ND + t];
        atomicAdd(&lred[0], mi * d * d);
    } else if (t < ND + 2) {
        int d2 = t - ND;
        float o = pb2[d2];
        for (int k = 0; k < HH; ++k) o += h2[k] * pw2[k * 2 + d2];
        float d = o - position_noise[idx * 2 + d2];
        atomicAdd(&lred[1], mi * d * d);
    }
    __syncthreads();
    if (t == 0) {
        atomicAdd(&accums[0], lred[0]);
        atomicAdd(&accums[1], lred[1]);
    }
}

// ---------------- masked mean pooling ----------------
__global__ void k_gemb(const float* __restrict__ state, const float* __restrict__ mask,
                       const float* __restrict__ scal, float* __restrict__ gemb) {
    int b = blockIdx.x;
    int t = threadIdx.x;
    float acc = 0.0f;
    for (int i = 0; i < NN; ++i) acc += state[(b * NN + i) * HH + t] * mask[b * NN + i];
    gemb[b * HH + t] = acc / fmaxf(scal[b * 4 + 2], 1.0f);
}

// ---------------- property MLP + final losses ----------------
__global__ void k_final(const float* __restrict__ gemb, const float* __restrict__ targets,
                        const float* __restrict__ pweights,
                        const float* __restrict__ w1, const float* __restrict__ b1,
                        const float* __restrict__ w2, const float* __restrict__ b2,
                        const float* __restrict__ w3, const float* __restrict__ b3,
                        const float* __restrict__ accums, const float* __restrict__ scal,
                        float* __restrict__ out) {
    int t = threadIdx.x;
    __shared__ float g[HH], h1[HH], h2[64];
    __shared__ float ploss_acc;
    if (t == 0) ploss_acc = 0.0f;
    for (int b = 0; b < BB; ++b) {
        __syncthreads();
        g[t] = gemb[b * HH + t];
        __syncthreads();
        float a = b1[t];
        for (int k = 0; k < HH; ++k) a += g[k] * w1[k * HH + t];
        h1[t] = silu_f(a);
        __syncthreads();
        if (t < 64) {
            float a2 = b2[t];
            for (int k = 0; k < HH; ++k) a2 += h1[k] * w2[k * 64 + t];
            h2[t] = silu_f(a2);
        }
        __syncthreads();
        if (t < 4) {
            float o = b3[t];
            for (int k = 0; k < 64; ++k) o += h2[k] * w3[k * 4 + t];
            float d = o - targets[b * 4 + t];
            atomicAdd(&ploss_acc, d * d * pweights[t]);
        }
    }
    __syncthreads();
    if (t == 0) {
        float msumt = fmaxf(scal[0 * 4 + 2] + scal[1 * 4 + 2], 1.0f);
        float noise = (accums[0] + accums[1]) / msumt;
        float prop = ploss_acc / (float)(BB * 4);
        out[0] = noise;
        out[1] = prop;
        out[2] = noise + prop;
    }
}

extern "C" void kernel_launch(void* const* d_in, const int* in_sizes, int n_in,
                              void* d_out, int out_size, void* d_ws, size_t ws_size,
                              hipStream_t stream) {
    const float* node_features  = (const float*)d_in[0];
    const float* positions      = (const float*)d_in[1];
    const float* mask           = (const float*)d_in[2];
    const float* condition      = (const float*)d_in[3];
    const float* targets        = (const float*)d_in[4];
    const float* pweights       = (const float*)d_in[5];
    const float* feature_noise  = (const float*)d_in[6];
    const float* position_noise = (const float*)d_in[7];
    const int*   timesteps      = (const int*)d_in[8];
    const float* time_w1 = (const float*)d_in[9];
    const float* time_b1 = (const float*)d_in[10];
    const float* time_w2 = (const float*)d_in[11];
    const float* time_b2 = (const float*)d_in[12];
    const float* cond_w1 = (const float*)d_in[13];
    const float* cond_b1 = (const float*)d_in[14];
    const float* cond_w2 = (const float*)d_in[15];
    const float* cond_b2 = (const float*)d_in[16];
    const float* nodep_w1 = (const float*)d_in[17];
    const float* nodep_b1 = (const float*)d_in[18];
    const float* nodep_w2 = (const float*)d_in[19];
    const float* nodep_b2 = (const float*)d_in[20];
    const float* edge_w1 = (const float*)d_in[21];
    const float* edge_b1 = (const float*)d_in[22];
    const float* edge_w2 = (const float*)d_in[23];
    const float* edge_b2 = (const float*)d_in[24];
    const float* nodem_w1 = (const float*)d_in[25];
    const float* nodem_b1 = (const float*)d_in[26];
    const float* nodem_w2 = (const float*)d_in[27];
    const float* nodem_b2 = (const float*)d_in[28];
    const float* feat_w1 = (const float*)d_in[29];
    const float* feat_b1 = (const float*)d_in[30];
    const float* feat_w2 = (const float*)d_in[31];
    const float* feat_b2 = (const float*)d_in[32];
    const float* pos_w1 = (const float*)d_in[33];
    const float* pos_b1 = (const float*)d_in[34];
    const float* pos_w2 = (const float*)d_in[35];
    const float* pos_b2 = (const float*)d_in[36];
    const float* prop_w1 = (const float*)d_in[37];
    const float* prop_b1 = (const float*)d_in[38];
    const float* prop_w2 = (const float*)d_in[39];
    const float* prop_b2 = (const float*)d_in[40];
    const float* prop_w3 = (const float*)d_in[41];
    const float* prop_b3 = (const float*)d_in[42];

    float* ws = (float*)d_ws;
    float* npos   = ws;                          // B*N*2
    float* state  = npos + BB * NN * 2;          // B*N*H
    float* dist   = state + BB * NN * HH;        // B*N*N
    float* aiA    = dist + BB * NN * NN;         // B*N*H
    float* ajA    = aiA + BB * NN * HH;          // B*N*H
    float* aiB    = ajA + BB * NN * HH;          // B*N*H
    float* ajB    = aiB + BB * NN * HH;          // B*N*H
    float* tc     = ajB + BB * NN * HH;          // B*H
    float* scal   = tc + BB * HH;                // B*4
    float* accums = scal + BB * 4;               // 2
    float* gemb   = accums + 2;                  // B*H

    float* outp = (float*)d_out;

    k_prep<<<BB, HH, 0, stream>>>(mask, condition, timesteps,
                                  time_w1, time_b1, time_w2, time_b2,
                                  cond_w1, cond_b1, cond_w2, cond_b2,
                                  tc, scal, accums);
    k_node_init<<<BB * NN, HH, 0, stream>>>(node_features, positions, feature_noise, position_noise,
                                            nodep_w1, nodep_b1, nodep_w2, nodep_b2,
                                            tc, scal, edge_w1, edge_b1, state, npos, aiA, ajA);
    k_dist<<<(BB * NN * NN + 255) / 256, 256, 0, stream>>>(npos, dist);

    for (int l = 0; l < LL; ++l) {
        const float* ew1l = edge_w1 + (size_t)l * (2 * HH + 1) * HH;
        const float* wd   = ew1l + (size_t)(2 * HH) * HH;
        const float* ew2  = edge_w2 + (size_t)l * HH * HH;
        const float* eb2  = edge_b2 + (size_t)l * HH;
        const float* nw1  = nodem_w1 + (size_t)l * 2 * HH * HH;
        const float* nb1  = nodem_b1 + (size_t)l * HH;
        const float* nw2  = nodem_w2 + (size_t)l * HH * HH;
        const float* nb2  = nodem_b2 + (size_t)l * HH;
        const float* ew1n = edge_w1 + (size_t)(l + 1) * (2 * HH + 1) * HH;
        const float* eb1n = edge_b1 + (size_t)(l + 1) * HH;

        const float* ai_in = (l & 1) ? aiB : aiA;
        const float* aj_in = (l & 1) ? ajB : ajA;
        float* ai_out = (l & 1) ? aiA : aiB;
        float* aj_out = (l & 1) ? ajA : ajB;

        if (l < LL - 1) {
            k_layer<false><<<BB * NN / NPB, 512, 0, stream>>>(
                ai_in, aj_in, ai_out, aj_out, dist, mask, scal, wd,
                ew2, eb2, nw1, nb1, nw2, nb2, ew1n, eb1n, state);
        } else {
            k_layer<true><<<BB * NN / NPB, 512, 0, stream>>>(
                ai_in, aj_in, ai_out, aj_out, dist, mask, scal, wd,
                ew2, eb2, nw1, nb1, nw2, nb2, edge_w1, edge_b1, state);
        }
    }

    k_heads<<<BB * NN, HH, 0, stream>>>(state, mask, feature_noise, position_noise,
                                        feat_w1, feat_b1, feat_w2, feat_b2,
                                        pos_w1, pos_b1, pos_w2, pos_b2, accums);
    k_gemb<<<BB, HH, 0, stream>>>(state, mask, scal, gemb);
    k_final<<<1, HH, 0, stream>>>(gemb, targets, pweights,
                                  prop_w1, prop_b1, prop_w2, prop_b2, prop_w3, prop_b3,
                                  accums, scal, outp);
}

// Round 6
// 334.446 us; speedup vs baseline: 1.3095x; 1.3095x over previous
//
#include <hip/hip_runtime.h>
#include <math.h>

#define BB 2
#define NN 384
#define ND 8
#define CD 16
#define HH 128
#define LL 4
#define TT 100
#define TOTN (BB * NN)   // 768

__device__ __forceinline__ float silu_f(float x) {
    float s = 1.0f / (1.0f + __expf(-x));
    return x * s;
}

// ---------------- per-batch prep: alpha_bar, mask sum, time+cond MLPs, zero accums ----------------
__global__ void k_prep(const float* __restrict__ mask, const float* __restrict__ condition,
                       const int* __restrict__ timesteps,
                       const float* __restrict__ time_w1, const float* __restrict__ time_b1,
                       const float* __restrict__ time_w2, const float* __restrict__ time_b2,
                       const float* __restrict__ cond_w1, const float* __restrict__ cond_b1,
                       const float* __restrict__ cond_w2, const float* __restrict__ cond_b2,
                       float* __restrict__ tc, float* __restrict__ scal, float* __restrict__ accums) {
    int b = blockIdx.x;
    int t = threadIdx.x; // 0..127
    __shared__ float sh[HH];
    __shared__ float sh2[HH];
    __shared__ float shc[CD];
    __shared__ float red[HH];

    if (b == 0 && t < 2) accums[t] = 0.0f;

    int ts = timesteps[b];
    float ab = 1.0f;
    for (int k = 0; k <= ts; ++k) {
        float beta = 1e-4f + (0.02f - 1e-4f) * ((float)k / (float)(TT - 1));
        ab *= (1.0f - beta);
    }
    if (t == 0) {
        scal[b * 4 + 0] = sqrtf(ab);
        scal[b * 4 + 1] = sqrtf(1.0f - ab);
    }
    float m = 0.0f;
    for (int j = t; j < NN; j += HH) m += mask[b * NN + j];
    red[t] = m;
    __syncthreads();
    for (int s = 64; s > 0; s >>= 1) {
        if (t < s) red[t] += red[t + s];
        __syncthreads();
    }
    if (t == 0) scal[b * 4 + 2] = red[0];

    const int half = HH / 2;
    float factor = logf(10000.0f) / (float)(half - 1);
    float tf = (float)ts;
    float temb;
    if (t < half) temb = sinf(tf * __expf(-factor * (float)t));
    else          temb = cosf(tf * __expf(-factor * (float)(t - half)));
    sh[t] = temb;
    if (t < CD) shc[t] = condition[b * CD + t];
    __syncthreads();

    float acc = time_b1[t];
    for (int k = 0; k < HH; ++k) acc += sh[k] * time_w1[k * HH + t];
    sh2[t] = silu_f(acc);
    __syncthreads();
    float acc2 = time_b2[t];
    for (int k = 0; k < HH; ++k) acc2 += sh2[k] * time_w2[k * HH + t];
    float acc3 = cond_b1[t];
    for (int k = 0; k < CD; ++k) acc3 += shc[k] * cond_w1[k * HH + t];
    __syncthreads();
    sh[t] = silu_f(acc3);
    __syncthreads();
    float acc4 = cond_b2[t];
    for (int k = 0; k < HH; ++k) acc4 += sh[k] * cond_w2[k * HH + t];

    tc[b * HH + t] = acc2 + acc4;
}

// ---------------- node init: 4 nodes/block, noising + nodep MLP + tc + layer-0 ai/aj ----------------
__global__ __launch_bounds__(256) void k_node_init(
    const float* __restrict__ node_features, const float* __restrict__ positions,
    const float* __restrict__ feature_noise, const float* __restrict__ position_noise,
    const float* __restrict__ nodep_w1, const float* __restrict__ nodep_b1,
    const float* __restrict__ nodep_w2, const float* __restrict__ nodep_b2,
    const float* __restrict__ tc, const float* __restrict__ scal,
    const float* __restrict__ ew1_0, const float* __restrict__ eb1_0,
    float* __restrict__ state, float* __restrict__ npos,
    float* __restrict__ ai0, float* __restrict__ aj0) {
    const int tid = threadIdx.x;
    const int t = tid & 127;
    const int g = tid >> 7;
    const int b0 = blockIdx.x * 4;
    const int b = b0 / NN;

    __shared__ __align__(16) float x[4][12];
    __shared__ __align__(16) float sh1[4][HH];
    __shared__ __align__(16) float sst[4][HH];
    __shared__ float sred[4][2][HH];

    if (tid < 40) {
        int n = tid / 10, c = tid % 10;
        int gn = b0 + n;
        float sab = scal[b * 4 + 0], s1ab = scal[b * 4 + 1];
        float v;
        if (c < ND) {
            v = sab * node_features[gn * ND + c] + s1ab * feature_noise[gn * ND + c];
        } else {
            int d = c - ND;
            v = sab * positions[gn * 2 + d] + s1ab * position_noise[gn * 2 + d];
            npos[gn * 2 + d] = v;
        }
        x[n][c] = v;
    }
    __syncthreads();

    for (int n = 2 * g; n <= 2 * g + 1; ++n) {
        float a = nodep_b1[t];
        #pragma unroll
        for (int k = 0; k < ND + 2; ++k) a += x[n][k] * nodep_w1[k * HH + t];
        sh1[n][t] = silu_f(a);
    }
    __syncthreads();

    // h1 @ nodep_w2
    {
        float a0 = 0, a1 = 0, a2 = 0, a3 = 0;
        const int k0 = g * 64;
        const float* wr = nodep_w2 + (size_t)k0 * HH + t;
        for (int kk = 0; kk < 64; kk += 4) {
            float w0 = wr[(kk + 0) * HH], w1 = wr[(kk + 1) * HH];
            float w2 = wr[(kk + 2) * HH], w3 = wr[(kk + 3) * HH];
            float4 s;
            s = *(const float4*)&sh1[0][k0 + kk]; a0 += s.x * w0 + s.y * w1 + s.z * w2 + s.w * w3;
            s = *(const float4*)&sh1[1][k0 + kk]; a1 += s.x * w0 + s.y * w1 + s.z * w2 + s.w * w3;
            s = *(const float4*)&sh1[2][k0 + kk]; a2 += s.x * w0 + s.y * w1 + s.z * w2 + s.w * w3;
            s = *(const float4*)&sh1[3][k0 + kk]; a3 += s.x * w0 + s.y * w1 + s.z * w2 + s.w * w3;
        }
        sred[0][g][t] = a0; sred[1][g][t] = a1; sred[2][g][t] = a2; sred[3][g][t] = a3;
    }
    __syncthreads();
    {
        float tcv = nodep_b2[t] + tc[b * HH + t];
        for (int n = 2 * g; n <= 2 * g + 1; ++n) {
            float st = sred[n][0][t] + sred[n][1][t] + tcv;
            state[(size_t)(b0 + n) * HH + t] = st;
            sst[n][t] = st;
        }
    }
    __syncthreads();

    // ai0 = sst @ ew1_0[:H] + eb1_0
    {
        float a0 = 0, a1 = 0, a2 = 0, a3 = 0;
        const int k0 = g * 64;
        const float* wr = ew1_0 + (size_t)k0 * HH + t;
        for (int kk = 0; kk < 64; kk += 4) {
            float w0 = wr[(kk + 0) * HH], w1 = wr[(kk + 1) * HH];
            float w2 = wr[(kk + 2) * HH], w3 = wr[(kk + 3) * HH];
            float4 s;
            s = *(const float4*)&sst[0][k0 + kk]; a0 += s.x * w0 + s.y * w1 + s.z * w2 + s.w * w3;
            s = *(const float4*)&sst[1][k0 + kk]; a1 += s.x * w0 + s.y * w1 + s.z * w2 + s.w * w3;
            s = *(const float4*)&sst[2][k0 + kk]; a2 += s.x * w0 + s.y * w1 + s.z * w2 + s.w * w3;
            s = *(const float4*)&sst[3][k0 + kk]; a3 += s.x * w0 + s.y * w1 + s.z * w2 + s.w * w3;
        }
        sred[0][g][t] = a0; sred[1][g][t] = a1; sred[2][g][t] = a2; sred[3][g][t] = a3;
    }
    __syncthreads();
    for (int n = 2 * g; n <= 2 * g + 1; ++n)
        ai0[(size_t)(b0 + n) * HH + t] = sred[n][0][t] + sred[n][1][t] + eb1_0[t];
    __syncthreads();
    // aj0 = sst @ ew1_0[H:2H]
    {
        float a0 = 0, a1 = 0, a2 = 0, a3 = 0;
        const int k0 = g * 64;
        const float* wr = ew1_0 + (size_t)(HH + k0) * HH + t;
        for (int kk = 0; kk < 64; kk += 4) {
            float w0 = wr[(kk + 0) * HH], w1 = wr[(kk + 1) * HH];
            float w2 = wr[(kk + 2) * HH], w3 = wr[(kk + 3) * HH];
            float4 s;
            s = *(const float4*)&sst[0][k0 + kk]; a0 += s.x * w0 + s.y * w1 + s.z * w2 + s.w * w3;
            s = *(const float4*)&sst[1][k0 + kk]; a1 += s.x * w0 + s.y * w1 + s.z * w2 + s.w * w3;
            s = *(const float4*)&sst[2][k0 + kk]; a2 += s.x * w0 + s.y * w1 + s.z * w2 + s.w * w3;
            s = *(const float4*)&sst[3][k0 + kk]; a3 += s.x * w0 + s.y * w1 + s.z * w2 + s.w * w3;
        }
        sred[0][g][t] = a0; sred[1][g][t] = a1; sred[2][g][t] = a2; sred[3][g][t] = a3;
    }
    __syncthreads();
    for (int n = 2 * g; n <= 2 * g + 1; ++n)
        aj0[(size_t)(b0 + n) * HH + t] = sred[n][0][t] + sred[n][1][t];
}

// ---------------- pairwise distances ----------------
__global__ void k_dist(const float* __restrict__ npos, float* __restrict__ dist) {
    int idx = blockIdx.x * blockDim.x + threadIdx.x;
    if (idx >= BB * NN * NN) return;
    int b = idx / (NN * NN);
    int r = idx % (NN * NN);
    int i = r / NN, j = r % NN;
    float dx = npos[(b * NN + i) * 2 + 0] - npos[(b * NN + j) * 2 + 0];
    float dy = npos[(b * NN + i) * 2 + 1] - npos[(b * NN + j) * 2 + 1];
    dist[idx] = sqrtf(dx * dx + dy * dy + 1e-12f);
}

// ---------------- edge hot loop: Sp[q][n][t] = sum_{j in quarter q} m_j silu(ai_n + aj_j + d_nj*wd) ----------------
__global__ __launch_bounds__(256) void k_edge(
    const float* __restrict__ ai, const float* __restrict__ aj,
    const float* __restrict__ dist, const float* __restrict__ mask,
    const float* __restrict__ wd, float* __restrict__ Sp) {
    const int tid = threadIdx.x;
    const int t = tid & 127;
    const int g = tid >> 7;           // 0..1
    const int blk = blockIdx.x;       // 1536 = 384 pairs * 4 quarters
    const int p = blk >> 2, q = blk & 3;
    const int n0 = p * 2, n1 = p * 2 + 1;
    const int b = n0 / NN;
    const int jb = q * 96;

    __shared__ __align__(16) float4 sdm[96];
    __shared__ float sred[2][2][HH];

    for (int i = tid; i < 96; i += 256) {
        int j = jb + i;
        sdm[i] = make_float4(dist[(size_t)n0 * NN + j], dist[(size_t)n1 * NN + j],
                             mask[b * NN + j], 0.0f);
    }
    const float av0 = ai[(size_t)n0 * HH + t];
    const float av1 = ai[(size_t)n1 * HH + t];
    const float wdt = wd[t];
    __syncthreads();

    const float* pa = aj + ((size_t)b * NN + jb) * HH + t;
    float acc0 = 0.0f, acc1 = 0.0f;
    #pragma unroll 4
    for (int i = g; i < 96; i += 2) {
        float4 dm = sdm[i];
        float a = pa[(size_t)i * HH];
        float v0 = av0 + a + dm.x * wdt;
        float v1 = av1 + a + dm.y * wdt;
        acc0 = fmaf(dm.z, silu_f(v0), acc0);
        acc1 = fmaf(dm.z, silu_f(v1), acc1);
    }
    sred[0][g][t] = acc0;
    sred[1][g][t] = acc1;
    __syncthreads();
    if (g == 0) Sp[((size_t)q * TOTN + n0) * HH + t] = sred[0][0][t] + sred[0][1][t];
    else        Sp[((size_t)q * TOTN + n1) * HH + t] = sred[1][0][t] + sred[1][1][t];
}

// ---------------- nodeup: agg GEMV + node MLP + state update + (next ai/aj | heads+losses) ----------------
template<bool LAST>
__global__ __launch_bounds__(256) void k_nodeup(
    const float* __restrict__ Sp, float* __restrict__ state,
    const float* __restrict__ mask, const float* __restrict__ scal,
    const float* __restrict__ ew2, const float* __restrict__ eb2,
    const float* __restrict__ nw1, const float* __restrict__ nb1,
    const float* __restrict__ nw2, const float* __restrict__ nb2,
    const float* __restrict__ ew1n, const float* __restrict__ eb1n,
    float* __restrict__ ai_out, float* __restrict__ aj_out,
    const float* __restrict__ fnoise, const float* __restrict__ pnoise,
    const float* __restrict__ fw1, const float* __restrict__ fb1,
    const float* __restrict__ fw2, const float* __restrict__ fb2,
    const float* __restrict__ pw1, const float* __restrict__ pb1,
    const float* __restrict__ pw2, const float* __restrict__ pb2,
    float* __restrict__ accums, float* __restrict__ gembp) {
    const int tid = threadIdx.x;
    const int t = tid & 127;
    const int g = tid >> 7;
    const int b0 = blockIdx.x * 4;
    const int b = b0 / NN;

    __shared__ __align__(16) float sS[4][HH];
    __shared__ __align__(16) float sst[4][HH];
    __shared__ __align__(16) float sagg[4][HH];
    __shared__ __align__(16) float sh[4][HH];
    __shared__ float sred[4][2][HH];
    __shared__ float lf, lp;

    // A: gather S partials + state
    for (int i = tid; i < 4 * HH; i += 256) {
        int n = i >> 7, tt = i & 127;
        int gn = b0 + n;
        sS[n][tt] = Sp[((size_t)0 * TOTN + gn) * HH + tt] + Sp[((size_t)1 * TOTN + gn) * HH + tt]
                  + Sp[((size_t)2 * TOTN + gn) * HH + tt] + Sp[((size_t)3 * TOTN + gn) * HH + tt];
        sst[n][tt] = state[(size_t)gn * HH + tt];
    }
    if (tid == 0) { lf = 0.0f; lp = 0.0f; }
    __syncthreads();

    // B: S @ ew2
    {
        float a0 = 0, a1 = 0, a2 = 0, a3 = 0;
        const int k0 = g * 64;
        const float* wr = ew2 + (size_t)k0 * HH + t;
        for (int kk = 0; kk < 64; kk += 4) {
            float w0 = wr[(kk + 0) * HH], w1 = wr[(kk + 1) * HH];
            float w2 = wr[(kk + 2) * HH], w3 = wr[(kk + 3) * HH];
            float4 s;
            s = *(const float4*)&sS[0][k0 + kk]; a0 += s.x * w0 + s.y * w1 + s.z * w2 + s.w * w3;
            s = *(const float4*)&sS[1][k0 + kk]; a1 += s.x * w0 + s.y * w1 + s.z * w2 + s.w * w3;
            s = *(const float4*)&sS[2][k0 + kk]; a2 += s.x * w0 + s.y * w1 + s.z * w2 + s.w * w3;
            s = *(const float4*)&sS[3][k0 + kk]; a3 += s.x * w0 + s.y * w1 + s.z * w2 + s.w * w3;
        }
        sred[0][g][t] = a0; sred[1][g][t] = a1; sred[2][g][t] = a2; sred[3][g][t] = a3;
    }
    __syncthreads();
    {
        const float msum = scal[b * 4 + 2];
        for (int n = 2 * g; n <= 2 * g + 1; ++n) {
            float mi = mask[b0 + n];
            float denom = fmaxf(mi * msum, 1.0f);
            float a = sred[n][0][t] + sred[n][1][t] + msum * eb2[t];
            sagg[n][t] = mi * a / denom;
        }
    }
    __syncthreads();

    // C: [st, agg] @ nw1
    {
        float a0 = 0, a1 = 0, a2 = 0, a3 = 0;
        const float* wr = nw1 + (size_t)(g * HH) * HH + t;
        const float (*inp)[HH] = g ? (const float (*)[HH])sagg : (const float (*)[HH])sst;
        for (int kk = 0; kk < HH; kk += 4) {
            float w0 = wr[(kk + 0) * HH], w1 = wr[(kk + 1) * HH];
            float w2 = wr[(kk + 2) * HH], w3 = wr[(kk + 3) * HH];
            float4 s;
            s = *(const float4*)&inp[0][kk]; a0 += s.x * w0 + s.y * w1 + s.z * w2 + s.w * w3;
            s = *(const float4*)&inp[1][kk]; a1 += s.x * w0 + s.y * w1 + s.z * w2 + s.w * w3;
            s = *(const float4*)&inp[2][kk]; a2 += s.x * w0 + s.y * w1 + s.z * w2 + s.w * w3;
            s = *(const float4*)&inp[3][kk]; a3 += s.x * w0 + s.y * w1 + s.z * w2 + s.w * w3;
        }
        sred[0][g][t] = a0; sred[1][g][t] = a1; sred[2][g][t] = a2; sred[3][g][t] = a3;
    }
    __syncthreads();
    for (int n = 2 * g; n <= 2 * g + 1; ++n)
        sh[n][t] = silu_f(sred[n][0][t] + sred[n][1][t] + nb1[t]);
    __syncthreads();

    // D: h @ nw2 ; state update
    {
        float a0 = 0, a1 = 0, a2 = 0, a3 = 0;
        const int k0 = g * 64;
        const float* wr = nw2 + (size_t)k0 * HH + t;
        for (int kk = 0; kk < 64; kk += 4) {
            float w0 = wr[(kk + 0) * HH], w1 = wr[(kk + 1) * HH];
            float w2 = wr[(kk + 2) * HH], w3 = wr[(kk + 3) * HH];
            float4 s;
            s = *(const float4*)&sh[0][k0 + kk]; a0 += s.x * w0 + s.y * w1 + s.z * w2 + s.w * w3;
            s = *(const float4*)&sh[1][k0 + kk]; a1 += s.x * w0 + s.y * w1 + s.z * w2 + s.w * w3;
            s = *(const float4*)&sh[2][k0 + kk]; a2 += s.x * w0 + s.y * w1 + s.z * w2 + s.w * w3;
            s = *(const float4*)&sh[3][k0 + kk]; a3 += s.x * w0 + s.y * w1 + s.z * w2 + s.w * w3;
        }
        sred[0][g][t] = a0; sred[1][g][t] = a1; sred[2][g][t] = a2; sred[3][g][t] = a3;
    }
    __syncthreads();
    for (int n = 2 * g; n <= 2 * g + 1; ++n) {
        int gn = b0 + n;
        float mi = mask[gn];
        float ns = sst[n][t] + (sred[n][0][t] + sred[n][1][t] + nb2[t]) * mi;
        state[(size_t)gn * HH + t] = ns;
        sst[n][t] = ns;
    }
    __syncthreads();

    if (!LAST) {
        // ai' = st' @ ew1n[:H] + eb1n
        {
            float a0 = 0, a1 = 0, a2 = 0, a3 = 0;
            const int k0 = g * 64;
            const float* wr = ew1n + (size_t)k0 * HH + t;
            for (int kk = 0; kk < 64; kk += 4) {
                float w0 = wr[(kk + 0) * HH], w1 = wr[(kk + 1) * HH];
                float w2 = wr[(kk + 2) * HH], w3 = wr[(kk + 3) * HH];
                float4 s;
                s = *(const float4*)&sst[0][k0 + kk]; a0 += s.x * w0 + s.y * w1 + s.z * w2 + s.w * w3;
                s = *(const float4*)&sst[1][k0 + kk]; a1 += s.x * w0 + s.y * w1 + s.z * w2 + s.w * w3;
                s = *(const float4*)&sst[2][k0 + kk]; a2 += s.x * w0 + s.y * w1 + s.z * w2 + s.w * w3;
                s = *(const float4*)&sst[3][k0 + kk]; a3 += s.x * w0 + s.y * w1 + s.z * w2 + s.w * w3;
            }
            sred[0][g][t] = a0; sred[1][g][t] = a1; sred[2][g][t] = a2; sred[3][g][t] = a3;
        }
        __syncthreads();
        for (int n = 2 * g; n <= 2 * g + 1; ++n)
            ai_out[(size_t)(b0 + n) * HH + t] = sred[n][0][t] + sred[n][1][t] + eb1n[t];
        __syncthreads();
        // aj' = st' @ ew1n[H:2H]
        {
            float a0 = 0, a1 = 0, a2 = 0, a3 = 0;
            const int k0 = g * 64;
            const float* wr = ew1n + (size_t)(HH + k0) * HH + t;
            for (int kk = 0; kk < 64; kk += 4) {
                float w0 = wr[(kk + 0) * HH], w1 = wr[(kk + 1) * HH];
                float w2 = wr[(kk + 2) * HH], w3 = wr[(kk + 3) * HH];
                float4 s;
                s = *(const float4*)&sst[0][k0 + kk]; a0 += s.x * w0 + s.y * w1 + s.z * w2 + s.w * w3;
                s = *(const float4*)&sst[1][k0 + kk]; a1 += s.x * w0 + s.y * w1 + s.z * w2 + s.w * w3;
                s = *(const float4*)&sst[2][k0 + kk]; a2 += s.x * w0 + s.y * w1 + s.z * w2 + s.w * w3;
                s = *(const float4*)&sst[3][k0 + kk]; a3 += s.x * w0 + s.y * w1 + s.z * w2 + s.w * w3;
            }
            sred[0][g][t] = a0; sred[1][g][t] = a1; sred[2][g][t] = a2; sred[3][g][t] = a3;
        }
        __syncthreads();
        for (int n = 2 * g; n <= 2 * g + 1; ++n)
            aj_out[(size_t)(b0 + n) * HH + t] = sred[n][0][t] + sred[n][1][t];
    } else {
        // heads: h1 = silu(st'@fw1+fb1) -> sS ; h2 = silu(st'@pw1+pb1) -> sagg
        {
            float a0 = 0, a1 = 0, a2 = 0, a3 = 0;
            const int k0 = g * 64;
            const float* wr = fw1 + (size_t)k0 * HH + t;
            for (int kk = 0; kk < 64; kk += 4) {
                float w0 = wr[(kk + 0) * HH], w1 = wr[(kk + 1) * HH];
                float w2 = wr[(kk + 2) * HH], w3 = wr[(kk + 3) * HH];
                float4 s;
                s = *(const float4*)&sst[0][k0 + kk]; a0 += s.x * w0 + s.y * w1 + s.z * w2 + s.w * w3;
                s = *(const float4*)&sst[1][k0 + kk]; a1 += s.x * w0 + s.y * w1 + s.z * w2 + s.w * w3;
                s = *(const float4*)&sst[2][k0 + kk]; a2 += s.x * w0 + s.y * w1 + s.z * w2 + s.w * w3;
                s = *(const float4*)&sst[3][k0 + kk]; a3 += s.x * w0 + s.y * w1 + s.z * w2 + s.w * w3;
            }
            sred[0][g][t] = a0; sred[1][g][t] = a1; sred[2][g][t] = a2; sred[3][g][t] = a3;
        }
        __syncthreads();
        for (int n = 2 * g; n <= 2 * g + 1; ++n)
            sS[n][t] = silu_f(sred[n][0][t] + sred[n][1][t] + fb1[t]);
        __syncthreads();
        {
            float a0 = 0, a1 = 0, a2 = 0, a3 = 0;
            const int k0 = g * 64;
            const float* wr = pw1 + (size_t)k0 * HH + t;
            for (int kk = 0; kk < 64; kk += 4) {
                float w0 = wr[(kk + 0) * HH], w1 = wr[(kk + 1) * HH];
                float w2 = wr[(kk + 2) * HH], w3 = wr[(kk + 3) * HH];
                float4 s;
                s = *(const float4*)&sst[0][k0 + kk]; a0 += s.x * w0 + s.y * w1 + s.z * w2 + s.w * w3;
                s = *(const float4*)&sst[1][k0 + kk]; a1 += s.x * w0 + s.y * w1 + s.z * w2 + s.w * w3;
                s = *(const float4*)&sst[2][k0 + kk]; a2 += s.x * w0 + s.y * w1 + s.z * w2 + s.w * w3;
                s = *(const float4*)&sst[3][k0 + kk]; a3 += s.x * w0 + s.y * w1 + s.z * w2 + s.w * w3;
            }
            sred[0][g][t] = a0; sred[1][g][t] = a1; sred[2][g][t] = a2; sred[3][g][t] = a3;
        }
        __syncthreads();
        for (int n = 2 * g; n <= 2 * g + 1; ++n)
            sagg[n][t] = silu_f(sred[n][0][t] + sred[n][1][t] + pb1[t]);
        __syncthreads();

        // small outputs + squared-error partials + gemb partial
        {
            int n = tid >> 6, lane = tid & 63;
            int gn = b0 + n;
            float mi = mask[gn];
            if (lane < ND) {
                float o = fb2[lane];
                for (int k = 0; k < HH; ++k) o += sS[n][k] * fw2[k * ND + lane];
                float d = o - fnoise[(size_t)gn * ND + lane];
                atomicAdd(&lf, mi * d * d);
            } else if (lane < ND + 2) {
                int c = lane - ND;
                float o = pb2[c];
                for (int k = 0; k < HH; ++k) o += sagg[n][k] * pw2[k * 2 + c];
                float d = o - pnoise[(size_t)gn * 2 + c];
                atomicAdd(&lp, mi * d * d);
            }
        }
        {
            float v = sst[2 * g][t] * mask[b0 + 2 * g] + sst[2 * g + 1][t] * mask[b0 + 2 * g + 1];
            sred[0][g][t] = v;
        }
        __syncthreads();
        if (g == 0) gembp[(size_t)blockIdx.x * HH + t] = sred[0][0][t] + sred[0][1][t];
        if (tid == 0) {
            atomicAdd(&accums[0], lf);
            atomicAdd(&accums[1], lp);
        }
    }
}

// ---------------- final: gemb reduce + property MLP + losses ----------------
__global__ void k_final(const float* __restrict__ gembp, const float* __restrict__ targets,
                        const float* __restrict__ pweights,
                        const float* __restrict__ w1, const float* __restrict__ b1,
                        const float* __restrict__ w2, const float* __restrict__ b2,
                        const float* __restrict__ w3, const float* __restrict__ b3,
                        const float* __restrict__ accums, const float* __restrict__ scal,
                        float* __restrict__ out) {
    int t = threadIdx.x;
    __shared__ float g[HH], h1[HH], h2[64];
    __shared__ float ploss_acc;
    if (t == 0) ploss_acc = 0.0f;
    for (int b = 0; b < BB; ++b) {
        __syncthreads();
        float acc = 0.0f;
        const float* gp = gembp + (size_t)b * 96 * HH + t;
        #pragma unroll 8
        for (int r = 0; r < 96; ++r) acc += gp[(size_t)r * HH];
        g[t] = acc / fmaxf(scal[b * 4 + 2], 1.0f);
        __syncthreads();
        float a = b1[t];
        for (int k = 0; k < HH; ++k) a += g[k] * w1[k * HH + t];
        h1[t] = silu_f(a);
        __syncthreads();
        if (t < 64) {
            float a2 = b2[t];
            for (int k = 0; k < HH; ++k) a2 += h1[k] * w2[k * 64 + t];
            h2[t] = silu_f(a2);
        }
        __syncthreads();
        if (t < 4) {
            float o = b3[t];
            for (int k = 0; k < 64; ++k) o += h2[k] * w3[k * 4 + t];
            float d = o - targets[b * 4 + t];
            atomicAdd(&ploss_acc, d * d * pweights[t]);
        }
    }
    __syncthreads();
    if (t == 0) {
        float msumt = fmaxf(scal[0 * 4 + 2] + scal[1 * 4 + 2], 1.0f);
        float noise = (accums[0] + accums[1]) / msumt;
        float prop = ploss_acc / (float)(BB * 4);
        out[0] = noise;
        out[1] = prop;
        out[2] = noise + prop;
    }
}

extern "C" void kernel_launch(void* const* d_in, const int* in_sizes, int n_in,
                              void* d_out, int out_size, void* d_ws, size_t ws_size,
                              hipStream_t stream) {
    const float* node_features  = (const float*)d_in[0];
    const float* positions      = (const float*)d_in[1];
    const float* mask           = (const float*)d_in[2];
    const float* condition     = (const float*)d_in[3];
    const float* targets        = (const float*)d_in[4];
    const float* pweights       = (const float*)d_in[5];
    const float* feature_noise  = (const float*)d_in[6];
    const float* position_noise = (const float*)d_in[7];
    const int*   timesteps      = (const int*)d_in[8];
    const float* time_w1 = (const float*)d_in[9];
    const float* time_b1 = (const float*)d_in[10];
    const float* time_w2 = (const float*)d_in[11];
    const float* time_b2 = (const float*)d_in[12];
    const float* cond_w1 = (const float*)d_in[13];
    const float* cond_b1 = (const float*)d_in[14];
    const float* cond_w2 = (const float*)d_in[15];
    const float* cond_b2 = (const float*)d_in[16];
    const float* nodep_w1 = (const float*)d_in[17];
    const float* nodep_b1 = (const float*)d_in[18];
    const float* nodep_w2 = (const float*)d_in[19];
    const float* nodep_b2 = (const float*)d_in[20];
    const float* edge_w1 = (const float*)d_in[21];
    const float* edge_b1 = (const float*)d_in[22];
    const float* edge_w2 = (const float*)d_in[23];
    const float* edge_b2 = (const float*)d_in[24];
    const float* nodem_w1 = (const float*)d_in[25];
    const float* nodem_b1 = (const float*)d_in[26];
    const float* nodem_w2 = (const float*)d_in[27];
    const float* nodem_b2 = (const float*)d_in[28];
    const float* feat_w1 = (const float*)d_in[29];
    const float* feat_b1 = (const float*)d_in[30];
    const float* feat_w2 = (const float*)d_in[31];
    const float* feat_b2 = (const float*)d_in[32];
    const float* pos_w1 = (const float*)d_in[33];
    const float* pos_b1 = (const float*)d_in[34];
    const float* pos_w2 = (const float*)d_in[35];
    const float* pos_b2 = (const float*)d_in[36];
    const float* prop_w1 = (const float*)d_in[37];
    const float* prop_b1 = (const float*)d_in[38];
    const float* prop_w2 = (const float*)d_in[39];
    const float* prop_b2 = (const float*)d_in[40];
    const float* prop_w3 = (const float*)d_in[41];
    const float* prop_b3 = (const float*)d_in[42];

    float* ws = (float*)d_ws;
    float* npos   = ws;                          // B*N*2
    float* state  = npos + BB * NN * 2;          // 768*128
    float* dist   = state + TOTN * HH;           // 768*384
    float* aiA    = dist + (size_t)TOTN * NN;    // 768*128
    float* ajA    = aiA + TOTN * HH;
    float* aiB    = ajA + TOTN * HH;
    float* ajB    = aiB + TOTN * HH;
    float* Sp     = ajB + TOTN * HH;             // 4*768*128
    float* tc     = Sp + 4 * TOTN * HH;          // B*H
    float* scal   = tc + BB * HH;                // B*4
    float* accums = scal + BB * 4;               // 2
    float* gembp  = accums + 2;                  // 192*128

    float* outp = (float*)d_out;

    k_prep<<<BB, HH, 0, stream>>>(mask, condition, timesteps,
                                  time_w1, time_b1, time_w2, time_b2,
                                  cond_w1, cond_b1, cond_w2, cond_b2,
                                  tc, scal, accums);
    k_node_init<<<TOTN / 4, 256, 0, stream>>>(node_features, positions, feature_noise, position_noise,
                                              nodep_w1, nodep_b1, nodep_w2, nodep_b2,
                                              tc, scal, edge_w1, edge_b1, state, npos, aiA, ajA);
    k_dist<<<(BB * NN * NN + 255) / 256, 256, 0, stream>>>(npos, dist);

    for (int l = 0; l < LL; ++l) {
        const float* ew1l = edge_w1 + (size_t)l * (2 * HH + 1) * HH;
        const float* wd   = ew1l + (size_t)(2 * HH) * HH;
        const float* ew2  = edge_w2 + (size_t)l * HH * HH;
        const float* eb2  = edge_b2 + (size_t)l * HH;
        const float* nw1  = nodem_w1 + (size_t)l * 2 * HH * HH;
        const float* nb1  = nodem_b1 + (size_t)l * HH;
        const float* nw2  = nodem_w2 + (size_t)l * HH * HH;
        const float* nb2  = nodem_b2 + (size_t)l * HH;
        const float* ew1n = edge_w1 + (size_t)(l + 1) * (2 * HH + 1) * HH;
        const float* eb1n = edge_b1 + (size_t)(l + 1) * HH;

        const float* ai_in = (l & 1) ? aiB : aiA;
        const float* aj_in = (l & 1) ? ajB : ajA;
        float* ai_out = (l & 1) ? aiA : aiB;
        float* aj_out = (l & 1) ? ajA : ajB;

        k_edge<<<TOTN / 2 * 4, 256, 0, stream>>>(ai_in, aj_in, dist, mask, wd, Sp);

        if (l < LL - 1) {
            k_nodeup<false><<<TOTN / 4, 256, 0, stream>>>(
                Sp, state, mask, scal, ew2, eb2, nw1, nb1, nw2, nb2, ew1n, eb1n,
                ai_out, aj_out,
                feature_noise, position_noise, feat_w1, feat_b1, feat_w2, feat_b2,
                pos_w1, pos_b1, pos_w2, pos_b2, accums, gembp);
        } else {
            k_nodeup<true><<<TOTN / 4, 256, 0, stream>>>(
                Sp, state, mask, scal, ew2, eb2, nw1, nb1, nw2, nb2, ew1n, eb1n,
                ai_out, aj_out,
                feature_noise, position_noise, feat_w1, feat_b1, feat_w2, feat_b2,
                pos_w1, pos_b1, pos_w2, pos_b2, accums, gembp);
        }
    }

    k_final<<<1, HH, 0, stream>>>(gembp, targets, pweights,
                                  prop_w1, prop_b1, prop_w2, prop_b2, prop_w3, prop_b3,
                                  accums, scal, outp);
}

// Round 8
// 320.078 us; speedup vs baseline: 1.3682x; 1.0449x over previous
//
#include <hip/hip_runtime.h>
#include <math.h>

#define BB 2
#define NN 384
#define ND 8
#define CD 16
#define HH 128
#define LL 4
#define TT 100
#define TOTN (BB * NN)   // 768

__device__ __forceinline__ float silu_f(float x) {
    float s = 1.0f / (1.0f + __expf(-x));
    return x * s;
}

// ---------------- per-batch prep: alpha_bar, mask sum, time+cond MLPs, zero accums ----------------
__global__ void k_prep(const float* __restrict__ mask, const float* __restrict__ condition,
                       const int* __restrict__ timesteps,
                       const float* __restrict__ time_w1, const float* __restrict__ time_b1,
                       const float* __restrict__ time_w2, const float* __restrict__ time_b2,
                       const float* __restrict__ cond_w1, const float* __restrict__ cond_b1,
                       const float* __restrict__ cond_w2, const float* __restrict__ cond_b2,
                       float* __restrict__ tc, float* __restrict__ scal, float* __restrict__ accums) {
    int b = blockIdx.x;
    int t = threadIdx.x; // 0..127
    __shared__ float sh[HH];
    __shared__ float sh2[HH];
    __shared__ float shc[CD];
    __shared__ float red[HH];

    if (b == 0 && t < 2) accums[t] = 0.0f;

    int ts = timesteps[b];
    float ab = 1.0f;
    for (int k = 0; k <= ts; ++k) {
        float beta = 1e-4f + (0.02f - 1e-4f) * ((float)k / (float)(TT - 1));
        ab *= (1.0f - beta);
    }
    if (t == 0) {
        scal[b * 4 + 0] = sqrtf(ab);
        scal[b * 4 + 1] = sqrtf(1.0f - ab);
    }
    float m = 0.0f;
    for (int j = t; j < NN; j += HH) m += mask[b * NN + j];
    red[t] = m;
    __syncthreads();
    for (int s = 64; s > 0; s >>= 1) {
        if (t < s) red[t] += red[t + s];
        __syncthreads();
    }
    if (t == 0) scal[b * 4 + 2] = red[0];

    const int half = HH / 2;
    float factor = logf(10000.0f) / (float)(half - 1);
    float tf = (float)ts;
    float temb;
    if (t < half) temb = sinf(tf * __expf(-factor * (float)t));
    else          temb = cosf(tf * __expf(-factor * (float)(t - half)));
    sh[t] = temb;
    if (t < CD) shc[t] = condition[b * CD + t];
    __syncthreads();

    float acc = time_b1[t];
    for (int k = 0; k < HH; ++k) acc += sh[k] * time_w1[k * HH + t];
    sh2[t] = silu_f(acc);
    __syncthreads();
    float acc2 = time_b2[t];
    for (int k = 0; k < HH; ++k) acc2 += sh2[k] * time_w2[k * HH + t];
    float acc3 = cond_b1[t];
    for (int k = 0; k < CD; ++k) acc3 += shc[k] * cond_w1[k * HH + t];
    __syncthreads();
    sh[t] = silu_f(acc3);
    __syncthreads();
    float acc4 = cond_b2[t];
    for (int k = 0; k < HH; ++k) acc4 += sh[k] * cond_w2[k * HH + t];

    tc[b * HH + t] = acc2 + acc4;
}

// ---------------- node init: 4 nodes/block, noising + nodep MLP + tc + layer-0 ai/aj ----------------
__global__ __launch_bounds__(256) void k_node_init(
    const float* __restrict__ node_features, const float* __restrict__ positions,
    const float* __restrict__ feature_noise, const float* __restrict__ position_noise,
    const float* __restrict__ nodep_w1, const float* __restrict__ nodep_b1,
    const float* __restrict__ nodep_w2, const float* __restrict__ nodep_b2,
    const float* __restrict__ tc, const float* __restrict__ scal,
    const float* __restrict__ ew1_0, const float* __restrict__ eb1_0,
    float* __restrict__ state, float* __restrict__ npos,
    float* __restrict__ ai0, float* __restrict__ aj0) {
    const int tid = threadIdx.x;
    const int t = tid & 127;
    const int g = tid >> 7;
    const int b0 = blockIdx.x * 4;
    const int b = b0 / NN;

    __shared__ __align__(16) float x[4][12];
    __shared__ __align__(16) float sh1[4][HH];
    __shared__ __align__(16) float sst[4][HH];
    __shared__ float sred[4][2][HH];

    if (tid < 40) {
        int n = tid / 10, c = tid % 10;
        int gn = b0 + n;
        float sab = scal[b * 4 + 0], s1ab = scal[b * 4 + 1];
        float v;
        if (c < ND) {
            v = sab * node_features[gn * ND + c] + s1ab * feature_noise[gn * ND + c];
        } else {
            int d = c - ND;
            v = sab * positions[gn * 2 + d] + s1ab * position_noise[gn * 2 + d];
            npos[gn * 2 + d] = v;
        }
        x[n][c] = v;
    }
    __syncthreads();

    for (int n = 2 * g; n <= 2 * g + 1; ++n) {
        float a = nodep_b1[t];
        #pragma unroll
        for (int k = 0; k < ND + 2; ++k) a += x[n][k] * nodep_w1[k * HH + t];
        sh1[n][t] = silu_f(a);
    }
    __syncthreads();

    // h1 @ nodep_w2
    {
        float a0 = 0, a1 = 0, a2 = 0, a3 = 0;
        const int k0 = g * 64;
        const float* wr = nodep_w2 + (size_t)k0 * HH + t;
        for (int kk = 0; kk < 64; kk += 4) {
            float w0 = wr[(kk + 0) * HH], w1 = wr[(kk + 1) * HH];
            float w2 = wr[(kk + 2) * HH], w3 = wr[(kk + 3) * HH];
            float4 s;
            s = *(const float4*)&sh1[0][k0 + kk]; a0 += s.x * w0 + s.y * w1 + s.z * w2 + s.w * w3;
            s = *(const float4*)&sh1[1][k0 + kk]; a1 += s.x * w0 + s.y * w1 + s.z * w2 + s.w * w3;
            s = *(const float4*)&sh1[2][k0 + kk]; a2 += s.x * w0 + s.y * w1 + s.z * w2 + s.w * w3;
            s = *(const float4*)&sh1[3][k0 + kk]; a3 += s.x * w0 + s.y * w1 + s.z * w2 + s.w * w3;
        }
        sred[0][g][t] = a0; sred[1][g][t] = a1; sred[2][g][t] = a2; sred[3][g][t] = a3;
    }
    __syncthreads();
    {
        float tcv = nodep_b2[t] + tc[b * HH + t];
        for (int n = 2 * g; n <= 2 * g + 1; ++n) {
            float st = sred[n][0][t] + sred[n][1][t] + tcv;
            state[(size_t)(b0 + n) * HH + t] = st;
            sst[n][t] = st;
        }
    }
    __syncthreads();

    // ai0 = sst @ ew1_0[:H] + eb1_0
    {
        float a0 = 0, a1 = 0, a2 = 0, a3 = 0;
        const int k0 = g * 64;
        const float* wr = ew1_0 + (size_t)k0 * HH + t;
        for (int kk = 0; kk < 64; kk += 4) {
            float w0 = wr[(kk + 0) * HH], w1 = wr[(kk + 1) * HH];
            float w2 = wr[(kk + 2) * HH], w3 = wr[(kk + 3) * HH];
            float4 s;
            s = *(const float4*)&sst[0][k0 + kk]; a0 += s.x * w0 + s.y * w1 + s.z * w2 + s.w * w3;
            s = *(const float4*)&sst[1][k0 + kk]; a1 += s.x * w0 + s.y * w1 + s.z * w2 + s.w * w3;
            s = *(const float4*)&sst[2][k0 + kk]; a2 += s.x * w0 + s.y * w1 + s.z * w2 + s.w * w3;
            s = *(const float4*)&sst[3][k0 + kk]; a3 += s.x * w0 + s.y * w1 + s.z * w2 + s.w * w3;
        }
        sred[0][g][t] = a0; sred[1][g][t] = a1; sred[2][g][t] = a2; sred[3][g][t] = a3;
    }
    __syncthreads();
    for (int n = 2 * g; n <= 2 * g + 1; ++n)
        ai0[(size_t)(b0 + n) * HH + t] = sred[n][0][t] + sred[n][1][t] + eb1_0[t];
    __syncthreads();
    // aj0 = sst @ ew1_0[H:2H]
    {
        float a0 = 0, a1 = 0, a2 = 0, a3 = 0;
        const int k0 = g * 64;
        const float* wr = ew1_0 + (size_t)(HH + k0) * HH + t;
        for (int kk = 0; kk < 64; kk += 4) {
            float w0 = wr[(kk + 0) * HH], w1 = wr[(kk + 1) * HH];
            float w2 = wr[(kk + 2) * HH], w3 = wr[(kk + 3) * HH];
            float4 s;
            s = *(const float4*)&sst[0][k0 + kk]; a0 += s.x * w0 + s.y * w1 + s.z * w2 + s.w * w3;
            s = *(const float4*)&sst[1][k0 + kk]; a1 += s.x * w0 + s.y * w1 + s.z * w2 + s.w * w3;
            s = *(const float4*)&sst[2][k0 + kk]; a2 += s.x * w0 + s.y * w1 + s.z * w2 + s.w * w3;
            s = *(const float4*)&sst[3][k0 + kk]; a3 += s.x * w0 + s.y * w1 + s.z * w2 + s.w * w3;
        }
        sred[0][g][t] = a0; sred[1][g][t] = a1; sred[2][g][t] = a2; sred[3][g][t] = a3;
    }
    __syncthreads();
    for (int n = 2 * g; n <= 2 * g + 1; ++n)
        aj0[(size_t)(b0 + n) * HH + t] = sred[n][0][t] + sred[n][1][t];
}

// ---------------- pairwise distances ----------------
__global__ void k_dist(const float* __restrict__ npos, float* __restrict__ dist) {
    int idx = blockIdx.x * blockDim.x + threadIdx.x;
    if (idx >= BB * NN * NN) return;
    int b = idx / (NN * NN);
    int r = idx % (NN * NN);
    int i = r / NN, j = r % NN;
    float dx = npos[(b * NN + i) * 2 + 0] - npos[(b * NN + j) * 2 + 0];
    float dy = npos[(b * NN + i) * 2 + 1] - npos[(b * NN + j) * 2 + 1];
    dist[idx] = sqrtf(dx * dx + dy * dy + 1e-12f);
}

// ---------------- edge hot loop: Sp[q][n][t] = sum_{j in quarter q} m_j silu(ai_n + aj_j + d_nj*wd) ----------------
__global__ __launch_bounds__(256) void k_edge(
    const float* __restrict__ ai, const float* __restrict__ aj,
    const float* __restrict__ dist, const float* __restrict__ mask,
    const float* __restrict__ wd, float* __restrict__ Sp) {
    const int tid = threadIdx.x;
    const int t = tid & 127;
    const int g = tid >> 7;           // 0..1
    const int blk = blockIdx.x;       // 1536 = 384 pairs * 4 quarters
    const int p = blk >> 2, q = blk & 3;
    const int n0 = p * 2, n1 = p * 2 + 1;
    const int b = n0 / NN;
    const int jb = q * 96;

    __shared__ __align__(16) float4 sdm[96];
    __shared__ float sred[2][2][HH];

    for (int i = tid; i < 96; i += 256) {
        int j = jb + i;
        sdm[i] = make_float4(dist[(size_t)n0 * NN + j], dist[(size_t)n1 * NN + j],
                             mask[b * NN + j], 0.0f);
    }
    const float av0 = ai[(size_t)n0 * HH + t];
    const float av1 = ai[(size_t)n1 * HH + t];
    const float wdt = wd[t];
    __syncthreads();

    const float* pa = aj + ((size_t)b * NN + jb) * HH + t;
    float acc0 = 0.0f, acc1 = 0.0f;
    #pragma unroll 4
    for (int i = g; i < 96; i += 2) {
        float4 dm = sdm[i];
        float a = pa[(size_t)i * HH];
        float v0 = av0 + a + dm.x * wdt;
        float v1 = av1 + a + dm.y * wdt;
        acc0 = fmaf(dm.z, silu_f(v0), acc0);
        acc1 = fmaf(dm.z, silu_f(v1), acc1);
    }
    sred[0][g][t] = acc0;
    sred[1][g][t] = acc1;
    __syncthreads();
    if (g == 0) Sp[((size_t)q * TOTN + n0) * HH + t] = sred[0][0][t] + sred[0][1][t];
    else        Sp[((size_t)q * TOTN + n1) * HH + t] = sred[1][0][t] + sred[1][1][t];
}

// ---------------- nodeup: 2 nodes/block, 512 threads, 4-way k-split GEMVs ----------------
template<bool LAST>
__global__ __launch_bounds__(512) void k_nodeup(
    const float* __restrict__ Sp, float* __restrict__ state,
    const float* __restrict__ mask, const float* __restrict__ scal,
    const float* __restrict__ ew2, const float* __restrict__ eb2,
    const float* __restrict__ nw1, const float* __restrict__ nb1,
    const float* __restrict__ nw2, const float* __restrict__ nb2,
    const float* __restrict__ ew1n, const float* __restrict__ eb1n,
    float* __restrict__ ai_out, float* __restrict__ aj_out,
    const float* __restrict__ fnoise, const float* __restrict__ pnoise,
    const float* __restrict__ fw1, const float* __restrict__ fb1,
    const float* __restrict__ fw2, const float* __restrict__ fb2,
    const float* __restrict__ pw1, const float* __restrict__ pb1,
    const float* __restrict__ pw2, const float* __restrict__ pb2,
    float* __restrict__ accums, float* __restrict__ gembp) {
    const int tid = threadIdx.x;
    const int t = tid & 127;
    const int g = tid >> 7;        // 0..3
    const int b0 = blockIdx.x * 2;
    const int b = b0 / NN;

    __shared__ __align__(16) float sS[2][HH];
    __shared__ __align__(16) float sst[2][HH];
    __shared__ __align__(16) float sagg[2][HH];
    __shared__ __align__(16) float sh[2][HH];
    __shared__ float sred[2][4][HH];
    __shared__ float lf, lp;

    // A: gather S partials + state
    if (tid < 2 * HH) {
        int n = tid >> 7, tt = tid & 127;
        int gn = b0 + n;
        sS[n][tt] = Sp[((size_t)0 * TOTN + gn) * HH + tt] + Sp[((size_t)1 * TOTN + gn) * HH + tt]
                  + Sp[((size_t)2 * TOTN + gn) * HH + tt] + Sp[((size_t)3 * TOTN + gn) * HH + tt];
        sst[n][tt] = state[(size_t)gn * HH + tt];
    }
    if (tid == 0) { lf = 0.0f; lp = 0.0f; }
    __syncthreads();

    // B: S @ ew2 (4-way k split, 32 each)
    {
        float a0 = 0, a1 = 0;
        const int k0 = g * 32;
        const float* wr = ew2 + (size_t)k0 * HH + t;
        for (int kk = 0; kk < 32; kk += 4) {
            float w0 = wr[(kk + 0) * HH], w1 = wr[(kk + 1) * HH];
            float w2 = wr[(kk + 2) * HH], w3 = wr[(kk + 3) * HH];
            float4 s;
            s = *(const float4*)&sS[0][k0 + kk]; a0 += s.x * w0 + s.y * w1 + s.z * w2 + s.w * w3;
            s = *(const float4*)&sS[1][k0 + kk]; a1 += s.x * w0 + s.y * w1 + s.z * w2 + s.w * w3;
        }
        sred[0][g][t] = a0; sred[1][g][t] = a1;
    }
    __syncthreads();
    if (g < 2) {
        const float msum = scal[b * 4 + 2];
        float mi = mask[b0 + g];
        float denom = fmaxf(mi * msum, 1.0f);
        float a = sred[g][0][t] + sred[g][1][t] + sred[g][2][t] + sred[g][3][t] + msum * eb2[t];
        sagg[g][t] = mi * a / denom;
    }
    __syncthreads();

    // C: [st, agg] @ nw1 (4-way row split, 64 each; g<2 -> st rows, g>=2 -> agg rows)
    {
        float a0 = 0, a1 = 0;
        const int r0 = g * 64;
        const float* wr = nw1 + (size_t)r0 * HH + t;
        const float (*inp)[HH] = (g < 2) ? (const float (*)[HH])sst : (const float (*)[HH])sagg;
        const int rb = (g & 1) * 64;
        for (int kk = 0; kk < 64; kk += 4) {
            float w0 = wr[(kk + 0) * HH], w1 = wr[(kk + 1) * HH];
            float w2 = wr[(kk + 2) * HH], w3 = wr[(kk + 3) * HH];
            float4 s;
            s = *(const float4*)&inp[0][rb + kk]; a0 += s.x * w0 + s.y * w1 + s.z * w2 + s.w * w3;
            s = *(const float4*)&inp[1][rb + kk]; a1 += s.x * w0 + s.y * w1 + s.z * w2 + s.w * w3;
        }
        sred[0][g][t] = a0; sred[1][g][t] = a1;
    }
    __syncthreads();
    if (g < 2) sh[g][t] = silu_f(sred[g][0][t] + sred[g][1][t] + sred[g][2][t] + sred[g][3][t] + nb1[t]);
    __syncthreads();

    // D: h @ nw2 ; state update
    {
        float a0 = 0, a1 = 0;
        const int k0 = g * 32;
        const float* wr = nw2 + (size_t)k0 * HH + t;
        for (int kk = 0; kk < 32; kk += 4) {
            float w0 = wr[(kk + 0) * HH], w1 = wr[(kk + 1) * HH];
            float w2 = wr[(kk + 2) * HH], w3 = wr[(kk + 3) * HH];
            float4 s;
            s = *(const float4*)&sh[0][k0 + kk]; a0 += s.x * w0 + s.y * w1 + s.z * w2 + s.w * w3;
            s = *(const float4*)&sh[1][k0 + kk]; a1 += s.x * w0 + s.y * w1 + s.z * w2 + s.w * w3;
        }
        sred[0][g][t] = a0; sred[1][g][t] = a1;
    }
    __syncthreads();
    if (g < 2) {
        int gn = b0 + g;
        float mi = mask[gn];
        float ns = sst[g][t] + (sred[g][0][t] + sred[g][1][t] + sred[g][2][t] + sred[g][3][t] + nb2[t]) * mi;
        state[(size_t)gn * HH + t] = ns;
        sst[g][t] = ns;
    }
    __syncthreads();

    if (!LAST) {
        // ai' = st' @ ew1n[:H] + eb1n
        {
            float a0 = 0, a1 = 0;
            const int k0 = g * 32;
            const float* wr = ew1n + (size_t)k0 * HH + t;
            for (int kk = 0; kk < 32; kk += 4) {
                float w0 = wr[(kk + 0) * HH], w1 = wr[(kk + 1) * HH];
                float w2 = wr[(kk + 2) * HH], w3 = wr[(kk + 3) * HH];
                float4 s;
                s = *(const float4*)&sst[0][k0 + kk]; a0 += s.x * w0 + s.y * w1 + s.z * w2 + s.w * w3;
                s = *(const float4*)&sst[1][k0 + kk]; a1 += s.x * w0 + s.y * w1 + s.z * w2 + s.w * w3;
            }
            sred[0][g][t] = a0; sred[1][g][t] = a1;
        }
        __syncthreads();
        if (g < 2) ai_out[(size_t)(b0 + g) * HH + t] =
            sred[g][0][t] + sred[g][1][t] + sred[g][2][t] + sred[g][3][t] + eb1n[t];
        __syncthreads();
        // aj' = st' @ ew1n[H:2H]
        {
            float a0 = 0, a1 = 0;
            const int k0 = g * 32;
            const float* wr = ew1n + (size_t)(HH + k0) * HH + t;
            for (int kk = 0; kk < 32; kk += 4) {
                float w0 = wr[(kk + 0) * HH], w1 = wr[(kk + 1) * HH];
                float w2 = wr[(kk + 2) * HH], w3 = wr[(kk + 3) * HH];
                float4 s;
                s = *(const float4*)&sst[0][k0 + kk]; a0 += s.x * w0 + s.y * w1 + s.z * w2 + s.w * w3;
                s = *(const float4*)&sst[1][k0 + kk]; a1 += s.x * w0 + s.y * w1 + s.z * w2 + s.w * w3;
            }
            sred[0][g][t] = a0; sred[1][g][t] = a1;
        }
        __syncthreads();
        if (g < 2) aj_out[(size_t)(b0 + g) * HH + t] =
            sred[g][0][t] + sred[g][1][t] + sred[g][2][t] + sred[g][3][t];
    } else {
        // heads: h1 = silu(st'@fw1+fb1) -> sS ; h2 = silu(st'@pw1+pb1) -> sagg
        {
            float a0 = 0, a1 = 0;
            const int k0 = g * 32;
            const float* wr = fw1 + (size_t)k0 * HH + t;
            for (int kk = 0; kk < 32; kk += 4) {
                float w0 = wr[(kk + 0) * HH], w1 = wr[(kk + 1) * HH];
                float w2 = wr[(kk + 2) * HH], w3 = wr[(kk + 3) * HH];
                float4 s;
                s = *(const float4*)&sst[0][k0 + kk]; a0 += s.x * w0 + s.y * w1 + s.z * w2 + s.w * w3;
                s = *(const float4*)&sst[1][k0 + kk]; a1 += s.x * w0 + s.y * w1 + s.z * w2 + s.w * w3;
            }
            sred[0][g][t] = a0; sred[1][g][t] = a1;
        }
        __syncthreads();
        if (g < 2) sS[g][t] = silu_f(sred[g][0][t] + sred[g][1][t] + sred[g][2][t] + sred[g][3][t] + fb1[t]);
        __syncthreads();
        {
            float a0 = 0, a1 = 0;
            const int k0 = g * 32;
            const float* wr = pw1 + (size_t)k0 * HH + t;
            for (int kk = 0; kk < 32; kk += 4) {
                float w0 = wr[(kk + 0) * HH], w1 = wr[(kk + 1) * HH];
                float w2 = wr[(kk + 2) * HH], w3 = wr[(kk + 3) * HH];
                float4 s;
                s = *(const float4*)&sst[0][k0 + kk]; a0 += s.x * w0 + s.y * w1 + s.z * w2 + s.w * w3;
                s = *(const float4*)&sst[1][k0 + kk]; a1 += s.x * w0 + s.y * w1 + s.z * w2 + s.w * w3;
            }
            sred[0][g][t] = a0; sred[1][g][t] = a1;
        }
        __syncthreads();
        if (g < 2) sagg[g][t] = silu_f(sred[g][0][t] + sred[g][1][t] + sred[g][2][t] + sred[g][3][t] + pb1[t]);
        __syncthreads();

        // small outputs + squared-error partials + gemb partial
        if (tid < 128) {
            int n = tid >> 6, lane = tid & 63;
            int gn = b0 + n;
            float mi = mask[gn];
            if (lane < ND) {
                float o = fb2[lane];
                for (int k = 0; k < HH; ++k) o += sS[n][k] * fw2[k * ND + lane];
                float d = o - fnoise[(size_t)gn * ND + lane];
                atomicAdd(&lf, mi * d * d);
            } else if (lane < ND + 2) {
                int c = lane - ND;
                float o = pb2[c];
                for (int k = 0; k < HH; ++k) o += sagg[n][k] * pw2[k * 2 + c];
                float d = o - pnoise[(size_t)gn * 2 + c];
                atomicAdd(&lp, mi * d * d);
            }
        }
        if (g == 0) {
            float v = sst[0][t] * mask[b0] + sst[1][t] * mask[b0 + 1];
            gembp[(size_t)blockIdx.x * HH + t] = v;
        }
        __syncthreads();
        if (tid == 0) {
            atomicAdd(&accums[0], lf);
            atomicAdd(&accums[1], lp);
        }
    }
}

// ---------------- final: gemb reduce (both batches parallel) + property MLP + losses ----------------
__global__ __launch_bounds__(256) void k_final(
    const float* __restrict__ gembp, const float* __restrict__ targets,
    const float* __restrict__ pweights,
    const float* __restrict__ w1, const float* __restrict__ b1,
    const float* __restrict__ w2, const float* __restrict__ b2,
    const float* __restrict__ w3, const float* __restrict__ b3,
    const float* __restrict__ accums, const float* __restrict__ scal,
    float* __restrict__ out) {
    const int tid = threadIdx.x;
    const int t = tid & 127;
    const int b = tid >> 7;     // 0..1
    __shared__ float g2[BB][HH], h1[BB][HH], h2[BB][64];
    __shared__ float pl;
    if (tid == 0) pl = 0.0f;

    // reduce 192 gemb partials per batch (gembp laid out blocks 0..383, batch = blk/192)
    float acc = 0.0f;
    const float* gp = gembp + (size_t)b * 192 * HH + t;
    #pragma unroll 8
    for (int r = 0; r < 192; ++r) acc += gp[(size_t)r * HH];
    g2[b][t] = acc / fmaxf(scal[b * 4 + 2], 1.0f);
    __syncthreads();

    float a = b1[t];
    for (int k = 0; k < HH; ++k) a += g2[b][k] * w1[k * HH + t];
    h1[b][t] = silu_f(a);
    __syncthreads();
    if (t < 64) {
        float a2 = b2[t];
        for (int k = 0; k < HH; ++k) a2 += h1[b][k] * w2[k * 64 + t];
        h2[b][t] = silu_f(a2);
    }
    __syncthreads();
    if (t < 4) {
        float o = b3[t];
        for (int k = 0; k < 64; ++k) o += h2[b][k] * w3[k * 4 + t];
        float d = o - targets[b * 4 + t];
        atomicAdd(&pl, d * d * pweights[t]);
    }
    __syncthreads();
    if (tid == 0) {
        float msumt = fmaxf(scal[0 * 4 + 2] + scal[1 * 4 + 2], 1.0f);
        float noise = (accums[0] + accums[1]) / msumt;
        float prop = pl / (float)(BB * 4);
        out[0] = noise;
        out[1] = prop;
        out[2] = noise + prop;
    }
}

extern "C" void kernel_launch(void* const* d_in, const int* in_sizes, int n_in,
                              void* d_out, int out_size, void* d_ws, size_t ws_size,
                              hipStream_t stream) {
    const float* node_features  = (const float*)d_in[0];
    const float* positions      = (const float*)d_in[1];
    const float* mask           = (const float*)d_in[2];
    const float* condition     = (const float*)d_in[3];
    const float* targets        = (const float*)d_in[4];
    const float* pweights       = (const float*)d_in[5];
    const float* feature_noise  = (const float*)d_in[6];
    const float* position_noise = (const float*)d_in[7];
    const int*   timesteps      = (const int*)d_in[8];
    const float* time_w1 = (const float*)d_in[9];
    const float* time_b1 = (const float*)d_in[10];
    const float* time_w2 = (const float*)d_in[11];
    const float* time_b2 = (const float*)d_in[12];
    const float* cond_w1 = (const float*)d_in[13];
    const float* cond_b1 = (const float*)d_in[14];
    const float* cond_w2 = (const float*)d_in[15];
    const float* cond_b2 = (const float*)d_in[16];
    const float* nodep_w1 = (const float*)d_in[17];
    const float* nodep_b1 = (const float*)d_in[18];
    const float* nodep_w2 = (const float*)d_in[19];
    const float* nodep_b2 = (const float*)d_in[20];
    const float* edge_w1 = (const float*)d_in[21];
    const float* edge_b1 = (const float*)d_in[22];
    const float* edge_w2 = (const float*)d_in[23];
    const float* edge_b2 = (const float*)d_in[24];
    const float* nodem_w1 = (const float*)d_in[25];
    const float* nodem_b1 = (const float*)d_in[26];
    const float* nodem_w2 = (const float*)d_in[27];
    const float* nodem_b2 = (const float*)d_in[28];
    const float* feat_w1 = (const float*)d_in[29];
    const float* feat_b1 = (const float*)d_in[30];
    const float* feat_w2 = (const float*)d_in[31];
    const float* feat_b2 = (const float*)d_in[32];
    const float* pos_w1 = (const float*)d_in[33];
    const float* pos_b1 = (const float*)d_in[34];
    const float* pos_w2 = (const float*)d_in[35];
    const float* pos_b2 = (const float*)d_in[36];
    const float* prop_w1 = (const float*)d_in[37];
    const float* prop_b1 = (const float*)d_in[38];
    const float* prop_w2 = (const float*)d_in[39];
    const float* prop_b2 = (const float*)d_in[40];
    const float* prop_w3 = (const float*)d_in[41];
    const float* prop_b3 = (const float*)d_in[42];

    float* ws = (float*)d_ws;
    float* npos   = ws;                          // B*N*2
    float* state  = npos + BB * NN * 2;          // 768*128
    float* dist   = state + TOTN * HH;           // 768*384
    float* aiA    = dist + (size_t)TOTN * NN;    // 768*128
    float* ajA    = aiA + TOTN * HH;
    float* aiB    = ajA + TOTN * HH;
    float* ajB    = aiB + TOTN * HH;
    float* Sp     = ajB + TOTN * HH;             // 4*768*128
    float* tc     = Sp + 4 * TOTN * HH;          // B*H
    float* scal   = tc + BB * HH;                // B*4
    float* accums = scal + BB * 4;               // 2
    float* gembp  = accums + 2;                  // 384*128

    float* outp = (float*)d_out;

    k_prep<<<BB, HH, 0, stream>>>(mask, condition, timesteps,
                                  time_w1, time_b1, time_w2, time_b2,
                                  cond_w1, cond_b1, cond_w2, cond_b2,
                                  tc, scal, accums);
    k_node_init<<<TOTN / 4, 256, 0, stream>>>(node_features, positions, feature_noise, position_noise,
                                              nodep_w1, nodep_b1, nodep_w2, nodep_b2,
                                              tc, scal, edge_w1, edge_b1, state, npos, aiA, ajA);
    k_dist<<<(BB * NN * NN + 255) / 256, 256, 0, stream>>>(npos, dist);

    for (int l = 0; l < LL; ++l) {
        const float* ew1l = edge_w1 + (size_t)l * (2 * HH + 1) * HH;
        const float* wd   = ew1l + (size_t)(2 * HH) * HH;
        const float* ew2  = edge_w2 + (size_t)l * HH * HH;
        const float* eb2  = edge_b2 + (size_t)l * HH;
        const float* nw1  = nodem_w1 + (size_t)l * 2 * HH * HH;
        const float* nb1  = nodem_b1 + (size_t)l * HH;
        const float* nw2  = nodem_w2 + (size_t)l * HH * HH;
        const float* nb2  = nodem_b2 + (size_t)l * HH;
        const float* ew1n = edge_w1 + (size_t)(l + 1) * (2 * HH + 1) * HH;
        const float* eb1n = edge_b1 + (size_t)(l + 1) * HH;

        const float* ai_in = (l & 1) ? aiB : aiA;
        const float* aj_in = (l & 1) ? ajB : ajA;
        float* ai_out = (l & 1) ? aiA : aiB;
        float* aj_out = (l & 1) ? ajA : ajB;

        k_edge<<<TOTN / 2 * 4, 256, 0, stream>>>(ai_in, aj_in, dist, mask, wd, Sp);

        if (l < LL - 1) {
            k_nodeup<false><<<TOTN / 2, 512, 0, stream>>>(
                Sp, state, mask, scal, ew2, eb2, nw1, nb1, nw2, nb2, ew1n, eb1n,
                ai_out, aj_out,
                feature_noise, position_noise, feat_w1, feat_b1, feat_w2, feat_b2,
                pos_w1, pos_b1, pos_w2, pos_b2, accums, gembp);
        } else {
            k_nodeup<true><<<TOTN / 2, 512, 0, stream>>>(
                Sp, state, mask, scal, ew2, eb2, nw1, nb1, nw2, nb2, ew1n, eb1n,
                ai_out, aj_out,
                feature_noise, position_noise, feat_w1, feat_b1, feat_w2, feat_b2,
                pos_w1, pos_b1, pos_w2, pos_b2, accums, gembp);
        }
    }

    k_final<<<1, 256, 0, stream>>>(gembp, targets, pweights,
                                   prop_w1, prop_b1, prop_w2, prop_b2, prop_w3, prop_b3,
                                   accums, scal, outp);
}